// Round 14
// baseline (113.702 us; speedup 1.0000x reference)
//
#include <hip/hip_runtime.h>

typedef _Float16 f16;
typedef __attribute__((ext_vector_type(4))) _Float16 f16x4;
typedef __attribute__((ext_vector_type(8))) _Float16 f16x8;
typedef __attribute__((ext_vector_type(4))) float f32x4;

#define MFMA32(a,b,c) __builtin_amdgcn_mfma_f32_16x16x32_f16((a),(b),(c),0,0,0)
#define MFMA16(a,b,c) __builtin_amdgcn_mfma_f32_16x16x16f16((a),(b),(c),0,0,0)

// ---- pre-kernel: pack weights into per-lane f16 fragments in ws (as R12/R13).
__global__ void wprep(const float* __restrict__ Wq, const float* __restrict__ Wk,
                      const float* __restrict__ Wv, const float* __restrict__ Wp,
                      f16* __restrict__ ws)
{
    const int t = threadIdx.x;
    const int lane = t & 63;
    const float* Wm[4] = {Wq, Wk, Wv, Wp};
    #pragma unroll
    for (int j = 0; j < 8; ++j) {
        const int c = (t >> 6) * 8 + j;
        const int m = c >> 3, ob = (c >> 1) & 3, s = c & 1;
        const float* src = Wm[m] + (ob * 16 + (lane & 15)) * 64 + 8 * (lane >> 4) + 32 * s;
        f32x4 a4 = *(const f32x4*)src;
        f32x4 b4 = *(const f32x4*)(src + 4);
        f16x8 h;
        #pragma unroll
        for (int ii = 0; ii < 8; ++ii) h[ii] = (f16)(ii < 4 ? a4[ii] : b4[ii - 4]);
        *(f16x8*)(ws + c * 512 + lane * 8) = h;
    }
    #pragma unroll
    for (int j = 0; j < 4; ++j) {
        const int f = (t >> 6) * 4 + j;
        const int oc = f >> 2, hh = f & 3;
        f32x4 wv = *(const f32x4*)(Wp + (oc * 16 + (lane & 15)) * 64 + 16 * hh + 4 * (lane >> 4));
        f16x4 h4;
        #pragma unroll
        for (int r = 0; r < 4; ++r) h4[r] = (f16)wv[r];
        *(f16x4*)(ws + 16384 + f * 256 + lane * 4) = h4;
    }
}

// R14: TWO quads per block (grid 1024), software-pipelined: quad1's gather is issued
// after quad0's attention so its HBM latency hides under quad0's tail. Halves the
// per-CU count of unhidden gather stalls + per-block fixed costs (R6-R13 showed
// intra-block micro-structure is not the limiter; grid shape never varied before).
// Body per quad = R13: LDS 32KB tile xw->vv (same-wave alias), in-reg ot (K16 A-frag
// identity), ones-MFMA softmax denominator, staged coalesced scatter via SG=XW alias.
#define GATHER16(RAW, B_, IDZ_, IH_, QX_)                                                     \
    _Pragma("unroll")                                                                         \
    for (int i = 0; i < 16; ++i) {                                                            \
        const int c = w * 16 + i;                                                             \
        RAW[i] = *(const f32x4*)(x + ((((B_*64 + c)*64 + IDZ_*4 + gz)*64) + IH_*4 + gy)*64    \
                                   + QX_*16 + gq*4);                                          \
    }

__global__ __launch_bounds__(256, 3)
void wsa3d(const float* __restrict__ x, const f16* __restrict__ wsf,
           const float* __restrict__ bq, const float* __restrict__ bk,
           const float* __restrict__ bv, const float* __restrict__ bp,
           float* __restrict__ out)
{
    __shared__ __align__(16) f16 XW[16384];
    float* const SG = (float*)XW;

    const int tid  = threadIdx.x;
    const int lane = tid & 63;
    const int w    = tid >> 6;
    const int g    = lane >> 4;
    const int ln16 = lane & 15;
    const int key  = ln16 & 7;

    // XCD swizzle over 1024 blocks (128/XCD, contiguous); quads Q0 (even) and Q0+1
    // share (ih,idz,b) and cover adjacent x-quads.
    const int bid = blockIdx.x;
    const int Bp  = ((bid & 7) << 7) | (bid >> 3);
    const int Q0  = Bp * 2;
    const int qx0 = Q0 & 3, ih = (Q0 >> 2) & 15, idz = (Q0 >> 6) & 15, b = Q0 >> 10;
    const int qx1 = qx0 | 1;

    const float c_sc = 0.25f * 1.44269504088896340736f;  // scale * log2(e)
    const f32x4 z4 = {0.f, 0.f, 0.f, 0.f};
    const f16x4 ones = {(f16)1.f, (f16)1.f, (f16)1.f, (f16)1.f};
    const f16* ws2 = wsf + 16384;

    const int gz = (lane >> 4) & 3, gy = (lane >> 2) & 3, gq = lane & 3;

    f16x8 xf[4][2];
    f16x4 ot[4][4];
    f32x4 raw0[16], raw1[16];

    // ================= QUAD 0 =================
    GATHER16(raw0, b, idz, ih, qx0)

    #pragma unroll
    for (int lx = 0; lx < 4; ++lx) {
        const int t = gz * 16 + gy * 4 + lx;
        #pragma unroll
        for (int h2 = 0; h2 < 2; ++h2) {
            f16x8 pk;
            #pragma unroll
            for (int ii = 0; ii < 8; ++ii) pk[ii] = (f16)raw0[h2 * 8 + ii][lx];
            *(f16x8*)(XW + gq*4096 + t*64 + (((w*2 + h2) ^ (t & 7) ^ gq) << 3)) = pk;
        }
    }
    __syncthreads();   // B1-0

    #pragma unroll
    for (int lb = 0; lb < 4; ++lb)
        #pragma unroll
        for (int s = 0; s < 2; ++s)
            xf[lb][s] = *(const f16x8*)(XW + w*4096 + (lb*16 + ln16)*64 + (((g + 4*s) ^ key ^ w) << 3));

    #pragma unroll
    for (int ob = 0; ob < 4; ++ob) {
        f16x8 VF[2];
        #pragma unroll
        for (int s = 0; s < 2; ++s) VF[s] = *(const f16x8*)(wsf + (16 + ob*2 + s)*512 + lane*8);
        const float bvo = bv[ob * 16 + ln16];
        #pragma unroll
        for (int tb = 0; tb < 4; ++tb) {
            f32x4 a = z4;
            #pragma unroll
            for (int s = 0; s < 2; ++s) a = MFMA32(xf[tb][s], VF[s], a);
            f16x4 h4;
            #pragma unroll
            for (int r = 0; r < 4; ++r) h4[r] = (f16)(a[r] + bvo);
            *(f16x4*)(XW + w*4096 + (ob*16 + ln16)*64 + (((2*tb + (g >> 1)) ^ key ^ w) << 3) + 4*(g & 1)) = h4;
        }
    }

    #pragma unroll
    for (int h = 0; h < 4; ++h) {
        f16x8 QF[2], KF[2];
        #pragma unroll
        for (int s = 0; s < 2; ++s) {
            QF[s] = *(const f16x8*)(wsf + (h*2 + s)*512 + lane*8);
            KF[s] = *(const f16x8*)(wsf + (8 + h*2 + s)*512 + lane*8);
        }
        const f32x4 bqv = *(const f32x4*)(bq + h*16 + g*4);
        const f32x4 bkv = *(const f32x4*)(bk + h*16 + g*4);
        f16x4 qf[4], kf[4];
        #pragma unroll
        for (int lb = 0; lb < 4; ++lb) {
            f32x4 aq = z4, ak = z4;
            #pragma unroll
            for (int s = 0; s < 2; ++s) {
                aq = MFMA32(QF[s], xf[lb][s], aq);
                ak = MFMA32(KF[s], xf[lb][s], ak);
            }
            #pragma unroll
            for (int r = 0; r < 4; ++r) {
                qf[lb][r] = (f16)((aq[r] + bqv[r]) * c_sc);
                kf[lb][r] = (f16)(ak[r] + bkv[r]);
            }
        }
        f16x4 va[4];
        #pragma unroll
        for (int jb = 0; jb < 4; ++jb)
            va[jb] = *(const f16x4*)(XW + w*4096 + (16*h + ln16)*64 + (((2*jb + (g >> 1)) ^ key ^ w) << 3) + 4*(g & 1));
        #pragma unroll
        for (int ib = 0; ib < 4; ++ib) {
            f16x4 pf[4];
            #pragma unroll
            for (int jb = 0; jb < 4; ++jb) {
                f32x4 S = MFMA16(kf[jb], qf[ib], z4);
                #pragma unroll
                for (int r = 0; r < 4; ++r) pf[jb][r] = (f16)__builtin_amdgcn_exp2f(S[r]);
            }
            f32x4 sm = z4;
            #pragma unroll
            for (int jb = 0; jb < 4; ++jb) sm = MFMA16(ones, pf[jb], sm);
            f32x4 O = z4;
            #pragma unroll
            for (int jb = 0; jb < 4; ++jb) O = MFMA16(va[jb], pf[jb], O);
            const float inv = __builtin_amdgcn_rcpf(sm[0]);
            #pragma unroll
            for (int r = 0; r < 4; ++r) ot[h][ib][r] = (f16)(O[r] * inv);
        }
    }

    // ---- PREFETCH quad1's gather: latency hides under quad0's tail
    GATHER16(raw1, b, idz, ih, qx1)

    __syncthreads();   // B_alias-0: XW tiles dead -> SG

    #pragma unroll
    for (int half = 0; half < 2; ++half) {
        #pragma unroll
        for (int pp = 0; pp < 2; ++pp) {
            const int oc = half * 2 + pp;
            const float bpo = bp[oc * 16 + ln16];
            f16x4 wb[4];
            #pragma unroll
            for (int h = 0; h < 4; ++h)
                wb[h] = *(const f16x4*)(ws2 + (oc * 4 + h) * 256 + lane * 4);
            #pragma unroll
            for (int ib = 0; ib < 4; ++ib) {
                f32x4 a = z4;
                #pragma unroll
                for (int h = 0; h < 4; ++h) a = MFMA16(ot[h][ib], wb[h], a);
                #pragma unroll
                for (int r = 0; r < 4; ++r) a[r] += bpo;
                *(f32x4*)(SG + ((pp*4 + w)*16 + ln16)*64 + (((4*ib + g) ^ ln16 ^ w) << 2)) = a;
            }
        }
        __syncthreads();
        #pragma unroll
        for (int pp = 0; pp < 2; ++pp) {
            const int oc = half * 2 + pp;
            #pragma unroll
            for (int si = 0; si < 4; ++si) {
                const int o2 = w * 4 + si;
                f32x4 v4 = *(const f32x4*)(SG + ((pp*4 + gq)*16 + o2)*64 + (((gz*4 + gy) ^ o2 ^ gq) << 2));
                *(f32x4*)(out + ((((b*64 + oc*16 + o2)*64 + idz*4 + gz)*64) + ih*4 + gy)*64 + qx0*16 + gq*4) = v4;
            }
        }
        __syncthreads();   // after half0: stage-half1; after half1: frees SG for pack1
    }

    // ================= QUAD 1 =================
    #pragma unroll
    for (int lx = 0; lx < 4; ++lx) {
        const int t = gz * 16 + gy * 4 + lx;
        #pragma unroll
        for (int h2 = 0; h2 < 2; ++h2) {
            f16x8 pk;
            #pragma unroll
            for (int ii = 0; ii < 8; ++ii) pk[ii] = (f16)raw1[h2 * 8 + ii][lx];
            *(f16x8*)(XW + gq*4096 + t*64 + (((w*2 + h2) ^ (t & 7) ^ gq) << 3)) = pk;
        }
    }
    __syncthreads();   // B1-1

    #pragma unroll
    for (int lb = 0; lb < 4; ++lb)
        #pragma unroll
        for (int s = 0; s < 2; ++s)
            xf[lb][s] = *(const f16x8*)(XW + w*4096 + (lb*16 + ln16)*64 + (((g + 4*s) ^ key ^ w) << 3));

    #pragma unroll
    for (int ob = 0; ob < 4; ++ob) {
        f16x8 VF[2];
        #pragma unroll
        for (int s = 0; s < 2; ++s) VF[s] = *(const f16x8*)(wsf + (16 + ob*2 + s)*512 + lane*8);
        const float bvo = bv[ob * 16 + ln16];
        #pragma unroll
        for (int tb = 0; tb < 4; ++tb) {
            f32x4 a = z4;
            #pragma unroll
            for (int s = 0; s < 2; ++s) a = MFMA32(xf[tb][s], VF[s], a);
            f16x4 h4;
            #pragma unroll
            for (int r = 0; r < 4; ++r) h4[r] = (f16)(a[r] + bvo);
            *(f16x4*)(XW + w*4096 + (ob*16 + ln16)*64 + (((2*tb + (g >> 1)) ^ key ^ w) << 3) + 4*(g & 1)) = h4;
        }
    }

    #pragma unroll
    for (int h = 0; h < 4; ++h) {
        f16x8 QF[2], KF[2];
        #pragma unroll
        for (int s = 0; s < 2; ++s) {
            QF[s] = *(const f16x8*)(wsf + (h*2 + s)*512 + lane*8);
            KF[s] = *(const f16x8*)(wsf + (8 + h*2 + s)*512 + lane*8);
        }
        const f32x4 bqv = *(const f32x4*)(bq + h*16 + g*4);
        const f32x4 bkv = *(const f32x4*)(bk + h*16 + g*4);
        f16x4 qf[4], kf[4];
        #pragma unroll
        for (int lb = 0; lb < 4; ++lb) {
            f32x4 aq = z4, ak = z4;
            #pragma unroll
            for (int s = 0; s < 2; ++s) {
                aq = MFMA32(QF[s], xf[lb][s], aq);
                ak = MFMA32(KF[s], xf[lb][s], ak);
            }
            #pragma unroll
            for (int r = 0; r < 4; ++r) {
                qf[lb][r] = (f16)((aq[r] + bqv[r]) * c_sc);
                kf[lb][r] = (f16)(ak[r] + bkv[r]);
            }
        }
        f16x4 va[4];
        #pragma unroll
        for (int jb = 0; jb < 4; ++jb)
            va[jb] = *(const f16x4*)(XW + w*4096 + (16*h + ln16)*64 + (((2*jb + (g >> 1)) ^ key ^ w) << 3) + 4*(g & 1));
        #pragma unroll
        for (int ib = 0; ib < 4; ++ib) {
            f16x4 pf[4];
            #pragma unroll
            for (int jb = 0; jb < 4; ++jb) {
                f32x4 S = MFMA16(kf[jb], qf[ib], z4);
                #pragma unroll
                for (int r = 0; r < 4; ++r) pf[jb][r] = (f16)__builtin_amdgcn_exp2f(S[r]);
            }
            f32x4 sm = z4;
            #pragma unroll
            for (int jb = 0; jb < 4; ++jb) sm = MFMA16(ones, pf[jb], sm);
            f32x4 O = z4;
            #pragma unroll
            for (int jb = 0; jb < 4; ++jb) O = MFMA16(va[jb], pf[jb], O);
            const float inv = __builtin_amdgcn_rcpf(sm[0]);
            #pragma unroll
            for (int r = 0; r < 4; ++r) ot[h][ib][r] = (f16)(O[r] * inv);
        }
    }
    __syncthreads();   // B_alias-1

    #pragma unroll
    for (int half = 0; half < 2; ++half) {
        #pragma unroll
        for (int pp = 0; pp < 2; ++pp) {
            const int oc = half * 2 + pp;
            const float bpo = bp[oc * 16 + ln16];
            f16x4 wb[4];
            #pragma unroll
            for (int h = 0; h < 4; ++h)
                wb[h] = *(const f16x4*)(ws2 + (oc * 4 + h) * 256 + lane * 4);
            #pragma unroll
            for (int ib = 0; ib < 4; ++ib) {
                f32x4 a = z4;
                #pragma unroll
                for (int h = 0; h < 4; ++h) a = MFMA16(ot[h][ib], wb[h], a);
                #pragma unroll
                for (int r = 0; r < 4; ++r) a[r] += bpo;
                *(f32x4*)(SG + ((pp*4 + w)*16 + ln16)*64 + (((4*ib + g) ^ ln16 ^ w) << 2)) = a;
            }
        }
        __syncthreads();
        #pragma unroll
        for (int pp = 0; pp < 2; ++pp) {
            const int oc = half * 2 + pp;
            #pragma unroll
            for (int si = 0; si < 4; ++si) {
                const int o2 = w * 4 + si;
                f32x4 v4 = *(const f32x4*)(SG + ((pp*4 + gq)*16 + o2)*64 + (((gz*4 + gy) ^ o2 ^ gq) << 2));
                *(f32x4*)(out + ((((b*64 + oc*16 + o2)*64 + idz*4 + gz)*64) + ih*4 + gy)*64 + qx1*16 + gq*4) = v4;
            }
        }
        if (half == 0) __syncthreads();
    }
}

extern "C" void kernel_launch(void* const* d_in, const int* in_sizes, int n_in,
                              void* d_out, int out_size, void* d_ws, size_t ws_size,
                              hipStream_t stream) {
    (void)in_sizes; (void)n_in; (void)out_size; (void)ws_size;
    const float* x  = (const float*)d_in[0];
    const float* Wq = (const float*)d_in[1];
    const float* bq = (const float*)d_in[2];
    const float* Wk = (const float*)d_in[3];
    const float* bk = (const float*)d_in[4];
    const float* Wv = (const float*)d_in[5];
    const float* bv = (const float*)d_in[6];
    const float* Wp = (const float*)d_in[7];
    const float* bp = (const float*)d_in[8];
    f16* wsf = (f16*)d_ws;
    wprep<<<1, 256, 0, stream>>>(Wq, Wk, Wv, Wp, wsf);
    wsa3d<<<1024, 256, 0, stream>>>(x, wsf, bq, bk, bv, bp, (float*)d_out);
}

// Round 15
// 82.563 us; speedup vs baseline: 1.3772x; 1.3772x over previous
//
#include <hip/hip_runtime.h>

typedef _Float16 f16;
typedef __attribute__((ext_vector_type(4))) _Float16 f16x4;
typedef __attribute__((ext_vector_type(8))) _Float16 f16x8;
typedef __attribute__((ext_vector_type(4))) float f32x4;

#define MFMA32(a,b,c) __builtin_amdgcn_mfma_f32_16x16x32_f16((a),(b),(c),0,0,0)
#define MFMA16(a,b,c) __builtin_amdgcn_mfma_f32_16x16x16f16((a),(b),(c),0,0,0)

// ---- pre-kernel: pack weights into per-lane f16 fragments in ws (as R12/R13).
__global__ void wprep(const float* __restrict__ Wq, const float* __restrict__ Wk,
                      const float* __restrict__ Wv, const float* __restrict__ Wp,
                      f16* __restrict__ ws)
{
    const int t = threadIdx.x;
    const int lane = t & 63;
    const float* Wm[4] = {Wq, Wk, Wv, Wp};
    #pragma unroll
    for (int j = 0; j < 8; ++j) {
        const int c = (t >> 6) * 8 + j;
        const int m = c >> 3, ob = (c >> 1) & 3, s = c & 1;
        const float* src = Wm[m] + (ob * 16 + (lane & 15)) * 64 + 8 * (lane >> 4) + 32 * s;
        f32x4 a4 = *(const f32x4*)src;
        f32x4 b4 = *(const f32x4*)(src + 4);
        f16x8 h;
        #pragma unroll
        for (int ii = 0; ii < 8; ++ii) h[ii] = (f16)(ii < 4 ? a4[ii] : b4[ii - 4]);
        *(f16x8*)(ws + c * 512 + lane * 8) = h;
    }
    #pragma unroll
    for (int j = 0; j < 4; ++j) {
        const int f = (t >> 6) * 4 + j;
        const int oc = f >> 2, hh = f & 3;
        f32x4 wv = *(const f32x4*)(Wp + (oc * 16 + (lane & 15)) * 64 + 16 * hh + 4 * (lane >> 4));
        f16x4 h4;
        #pragma unroll
        for (int r = 0; r < 4; ++r) h4[r] = (f16)wv[r];
        *(f16x4*)(ws + 16384 + f * 256 + lane * 4) = h4;
    }
}

// R15 = R14's 2-quad pipeline with the two R14 bugs fixed:
//  (1) quad1's gather is issued RIGHT AFTER B1-0 — next barrier (B_alias-0) is
//      ~3000cy away (vproj+attention), so the vmcnt(0) that __syncthreads emits
//      costs nothing (R14 issued it just before a barrier -> fully drained there).
//  (2) __launch_bounds__(256,2): register license 256 so raw1[16] (64 f32) stays
//      in regs (R14's bounds=3 + compiler heuristic spilled it: FETCH +84MB).
// Body per quad = R13: LDS 32KB tile xw->vv (same-wave alias), in-reg ot, ones-MFMA
// softmax denominator, staged coalesced scatter via SG=XW alias.
#define GATHER16(RAW, B_, IDZ_, IH_, QX_)                                                     \
    _Pragma("unroll")                                                                         \
    for (int i = 0; i < 16; ++i) {                                                            \
        const int c = w * 16 + i;                                                             \
        RAW[i] = *(const f32x4*)(x + ((((B_*64 + c)*64 + IDZ_*4 + gz)*64) + IH_*4 + gy)*64    \
                                   + QX_*16 + gq*4);                                          \
    }

__global__ __launch_bounds__(256, 2)
void wsa3d(const float* __restrict__ x, const f16* __restrict__ wsf,
           const float* __restrict__ bq, const float* __restrict__ bk,
           const float* __restrict__ bv, const float* __restrict__ bp,
           float* __restrict__ out)
{
    __shared__ __align__(16) f16 XW[16384];
    float* const SG = (float*)XW;

    const int tid  = threadIdx.x;
    const int lane = tid & 63;
    const int w    = tid >> 6;
    const int g    = lane >> 4;
    const int ln16 = lane & 15;
    const int key  = ln16 & 7;

    // XCD swizzle over 1024 blocks (128/XCD, contiguous); quads Q0/Q0+1 share
    // (ih,idz,b), adjacent x-quads.
    const int bid = blockIdx.x;
    const int Bp  = ((bid & 7) << 7) | (bid >> 3);
    const int Q0  = Bp * 2;
    const int qx0 = Q0 & 3, ih = (Q0 >> 2) & 15, idz = (Q0 >> 6) & 15, b = Q0 >> 10;
    const int qx1 = qx0 | 1;

    const float c_sc = 0.25f * 1.44269504088896340736f;  // scale * log2(e)
    const f32x4 z4 = {0.f, 0.f, 0.f, 0.f};
    const f16x4 ones = {(f16)1.f, (f16)1.f, (f16)1.f, (f16)1.f};
    const f16* ws2 = wsf + 16384;

    const int gz = (lane >> 4) & 3, gy = (lane >> 2) & 3, gq = lane & 3;

    f16x8 xf[4][2];
    f16x4 ot[4][4];
    f32x4 raw0[16], raw1[16];

    // ================= QUAD 0 =================
    GATHER16(raw0, b, idz, ih, qx0)

    #pragma unroll
    for (int lx = 0; lx < 4; ++lx) {
        const int t = gz * 16 + gy * 4 + lx;
        #pragma unroll
        for (int h2 = 0; h2 < 2; ++h2) {
            f16x8 pk;
            #pragma unroll
            for (int ii = 0; ii < 8; ++ii) pk[ii] = (f16)raw0[h2 * 8 + ii][lx];
            *(f16x8*)(XW + gq*4096 + t*64 + (((w*2 + h2) ^ (t & 7) ^ gq) << 3)) = pk;
        }
    }
    __syncthreads();   // B1-0

    // ---- PREFETCH quad1's gather NOW: ~3000cy of vproj+attention ahead of the
    //      next barrier hide the HBM latency; raw1 held in regs (bounds=2).
    GATHER16(raw1, b, idz, ih, qx1)

    #pragma unroll
    for (int lb = 0; lb < 4; ++lb)
        #pragma unroll
        for (int s = 0; s < 2; ++s)
            xf[lb][s] = *(const f16x8*)(XW + w*4096 + (lb*16 + ln16)*64 + (((g + 4*s) ^ key ^ w) << 3));

    #pragma unroll
    for (int ob = 0; ob < 4; ++ob) {
        f16x8 VF[2];
        #pragma unroll
        for (int s = 0; s < 2; ++s) VF[s] = *(const f16x8*)(wsf + (16 + ob*2 + s)*512 + lane*8);
        const float bvo = bv[ob * 16 + ln16];
        #pragma unroll
        for (int tb = 0; tb < 4; ++tb) {
            f32x4 a = z4;
            #pragma unroll
            for (int s = 0; s < 2; ++s) a = MFMA32(xf[tb][s], VF[s], a);
            f16x4 h4;
            #pragma unroll
            for (int r = 0; r < 4; ++r) h4[r] = (f16)(a[r] + bvo);
            *(f16x4*)(XW + w*4096 + (ob*16 + ln16)*64 + (((2*tb + (g >> 1)) ^ key ^ w) << 3) + 4*(g & 1)) = h4;
        }
    }

    #pragma unroll
    for (int h = 0; h < 4; ++h) {
        f16x8 QF[2], KF[2];
        #pragma unroll
        for (int s = 0; s < 2; ++s) {
            QF[s] = *(const f16x8*)(wsf + (h*2 + s)*512 + lane*8);
            KF[s] = *(const f16x8*)(wsf + (8 + h*2 + s)*512 + lane*8);
        }
        const f32x4 bqv = *(const f32x4*)(bq + h*16 + g*4);
        const f32x4 bkv = *(const f32x4*)(bk + h*16 + g*4);
        f16x4 qf[4], kf[4];
        #pragma unroll
        for (int lb = 0; lb < 4; ++lb) {
            f32x4 aq = z4, ak = z4;
            #pragma unroll
            for (int s = 0; s < 2; ++s) {
                aq = MFMA32(QF[s], xf[lb][s], aq);
                ak = MFMA32(KF[s], xf[lb][s], ak);
            }
            #pragma unroll
            for (int r = 0; r < 4; ++r) {
                qf[lb][r] = (f16)((aq[r] + bqv[r]) * c_sc);
                kf[lb][r] = (f16)(ak[r] + bkv[r]);
            }
        }
        f16x4 va[4];
        #pragma unroll
        for (int jb = 0; jb < 4; ++jb)
            va[jb] = *(const f16x4*)(XW + w*4096 + (16*h + ln16)*64 + (((2*jb + (g >> 1)) ^ key ^ w) << 3) + 4*(g & 1));
        #pragma unroll
        for (int ib = 0; ib < 4; ++ib) {
            f16x4 pf[4];
            #pragma unroll
            for (int jb = 0; jb < 4; ++jb) {
                f32x4 S = MFMA16(kf[jb], qf[ib], z4);
                #pragma unroll
                for (int r = 0; r < 4; ++r) pf[jb][r] = (f16)__builtin_amdgcn_exp2f(S[r]);
            }
            f32x4 sm = z4;
            #pragma unroll
            for (int jb = 0; jb < 4; ++jb) sm = MFMA16(ones, pf[jb], sm);
            f32x4 O = z4;
            #pragma unroll
            for (int jb = 0; jb < 4; ++jb) O = MFMA16(va[jb], pf[jb], O);
            const float inv = __builtin_amdgcn_rcpf(sm[0]);
            #pragma unroll
            for (int r = 0; r < 4; ++r) ot[h][ib][r] = (f16)(O[r] * inv);
        }
    }
    __syncthreads();   // B_alias-0: XW tiles dead -> SG (vmcnt(0) here is free: raw1 long since landed)

    #pragma unroll
    for (int half = 0; half < 2; ++half) {
        #pragma unroll
        for (int pp = 0; pp < 2; ++pp) {
            const int oc = half * 2 + pp;
            const float bpo = bp[oc * 16 + ln16];
            f16x4 wb[4];
            #pragma unroll
            for (int h = 0; h < 4; ++h)
                wb[h] = *(const f16x4*)(ws2 + (oc * 4 + h) * 256 + lane * 4);
            #pragma unroll
            for (int ib = 0; ib < 4; ++ib) {
                f32x4 a = z4;
                #pragma unroll
                for (int h = 0; h < 4; ++h) a = MFMA16(ot[h][ib], wb[h], a);
                #pragma unroll
                for (int r = 0; r < 4; ++r) a[r] += bpo;
                *(f32x4*)(SG + ((pp*4 + w)*16 + ln16)*64 + (((4*ib + g) ^ ln16 ^ w) << 2)) = a;
            }
        }
        __syncthreads();
        #pragma unroll
        for (int pp = 0; pp < 2; ++pp) {
            const int oc = half * 2 + pp;
            #pragma unroll
            for (int si = 0; si < 4; ++si) {
                const int o2 = w * 4 + si;
                f32x4 v4 = *(const f32x4*)(SG + ((pp*4 + gq)*16 + o2)*64 + (((gz*4 + gy) ^ o2 ^ gq) << 2));
                *(f32x4*)(out + ((((b*64 + oc*16 + o2)*64 + idz*4 + gz)*64) + ih*4 + gy)*64 + qx0*16 + gq*4) = v4;
            }
        }
        __syncthreads();   // after half0: stage half1; after half1: frees SG for pack1
    }

    // ================= QUAD 1 =================
    #pragma unroll
    for (int lx = 0; lx < 4; ++lx) {
        const int t = gz * 16 + gy * 4 + lx;
        #pragma unroll
        for (int h2 = 0; h2 < 2; ++h2) {
            f16x8 pk;
            #pragma unroll
            for (int ii = 0; ii < 8; ++ii) pk[ii] = (f16)raw1[h2 * 8 + ii][lx];
            *(f16x8*)(XW + gq*4096 + t*64 + (((w*2 + h2) ^ (t & 7) ^ gq) << 3)) = pk;
        }
    }
    __syncthreads();   // B1-1

    #pragma unroll
    for (int lb = 0; lb < 4; ++lb)
        #pragma unroll
        for (int s = 0; s < 2; ++s)
            xf[lb][s] = *(const f16x8*)(XW + w*4096 + (lb*16 + ln16)*64 + (((g + 4*s) ^ key ^ w) << 3));

    #pragma unroll
    for (int ob = 0; ob < 4; ++ob) {
        f16x8 VF[2];
        #pragma unroll
        for (int s = 0; s < 2; ++s) VF[s] = *(const f16x8*)(wsf + (16 + ob*2 + s)*512 + lane*8);
        const float bvo = bv[ob * 16 + ln16];
        #pragma unroll
        for (int tb = 0; tb < 4; ++tb) {
            f32x4 a = z4;
            #pragma unroll
            for (int s = 0; s < 2; ++s) a = MFMA32(xf[tb][s], VF[s], a);
            f16x4 h4;
            #pragma unroll
            for (int r = 0; r < 4; ++r) h4[r] = (f16)(a[r] + bvo);
            *(f16x4*)(XW + w*4096 + (ob*16 + ln16)*64 + (((2*tb + (g >> 1)) ^ key ^ w) << 3) + 4*(g & 1)) = h4;
        }
    }

    #pragma unroll
    for (int h = 0; h < 4; ++h) {
        f16x8 QF[2], KF[2];
        #pragma unroll
        for (int s = 0; s < 2; ++s) {
            QF[s] = *(const f16x8*)(wsf + (h*2 + s)*512 + lane*8);
            KF[s] = *(const f16x8*)(wsf + (8 + h*2 + s)*512 + lane*8);
        }
        const f32x4 bqv = *(const f32x4*)(bq + h*16 + g*4);
        const f32x4 bkv = *(const f32x4*)(bk + h*16 + g*4);
        f16x4 qf[4], kf[4];
        #pragma unroll
        for (int lb = 0; lb < 4; ++lb) {
            f32x4 aq = z4, ak = z4;
            #pragma unroll
            for (int s = 0; s < 2; ++s) {
                aq = MFMA32(QF[s], xf[lb][s], aq);
                ak = MFMA32(KF[s], xf[lb][s], ak);
            }
            #pragma unroll
            for (int r = 0; r < 4; ++r) {
                qf[lb][r] = (f16)((aq[r] + bqv[r]) * c_sc);
                kf[lb][r] = (f16)(ak[r] + bkv[r]);
            }
        }
        f16x4 va[4];
        #pragma unroll
        for (int jb = 0; jb < 4; ++jb)
            va[jb] = *(const f16x4*)(XW + w*4096 + (16*h + ln16)*64 + (((2*jb + (g >> 1)) ^ key ^ w) << 3) + 4*(g & 1));
        #pragma unroll
        for (int ib = 0; ib < 4; ++ib) {
            f16x4 pf[4];
            #pragma unroll
            for (int jb = 0; jb < 4; ++jb) {
                f32x4 S = MFMA16(kf[jb], qf[ib], z4);
                #pragma unroll
                for (int r = 0; r < 4; ++r) pf[jb][r] = (f16)__builtin_amdgcn_exp2f(S[r]);
            }
            f32x4 sm = z4;
            #pragma unroll
            for (int jb = 0; jb < 4; ++jb) sm = MFMA16(ones, pf[jb], sm);
            f32x4 O = z4;
            #pragma unroll
            for (int jb = 0; jb < 4; ++jb) O = MFMA16(va[jb], pf[jb], O);
            const float inv = __builtin_amdgcn_rcpf(sm[0]);
            #pragma unroll
            for (int r = 0; r < 4; ++r) ot[h][ib][r] = (f16)(O[r] * inv);
        }
    }
    __syncthreads();   // B_alias-1

    #pragma unroll
    for (int half = 0; half < 2; ++half) {
        #pragma unroll
        for (int pp = 0; pp < 2; ++pp) {
            const int oc = half * 2 + pp;
            const float bpo = bp[oc * 16 + ln16];
            f16x4 wb[4];
            #pragma unroll
            for (int h = 0; h < 4; ++h)
                wb[h] = *(const f16x4*)(ws2 + (oc * 4 + h) * 256 + lane * 4);
            #pragma unroll
            for (int ib = 0; ib < 4; ++ib) {
                f32x4 a = z4;
                #pragma unroll
                for (int h = 0; h < 4; ++h) a = MFMA16(ot[h][ib], wb[h], a);
                #pragma unroll
                for (int r = 0; r < 4; ++r) a[r] += bpo;
                *(f32x4*)(SG + ((pp*4 + w)*16 + ln16)*64 + (((4*ib + g) ^ ln16 ^ w) << 2)) = a;
            }
        }
        __syncthreads();
        #pragma unroll
        for (int pp = 0; pp < 2; ++pp) {
            const int oc = half * 2 + pp;
            #pragma unroll
            for (int si = 0; si < 4; ++si) {
                const int o2 = w * 4 + si;
                f32x4 v4 = *(const f32x4*)(SG + ((pp*4 + gq)*16 + o2)*64 + (((gz*4 + gy) ^ o2 ^ gq) << 2));
                *(f32x4*)(out + ((((b*64 + oc*16 + o2)*64 + idz*4 + gz)*64) + ih*4 + gy)*64 + qx1*16 + gq*4) = v4;
            }
        }
        if (half == 0) __syncthreads();
    }
}

extern "C" void kernel_launch(void* const* d_in, const int* in_sizes, int n_in,
                              void* d_out, int out_size, void* d_ws, size_t ws_size,
                              hipStream_t stream) {
    (void)in_sizes; (void)n_in; (void)out_size; (void)ws_size;
    const float* x  = (const float*)d_in[0];
    const float* Wq = (const float*)d_in[1];
    const float* bq = (const float*)d_in[2];
    const float* Wk = (const float*)d_in[3];
    const float* bk = (const float*)d_in[4];
    const float* Wv = (const float*)d_in[5];
    const float* bv = (const float*)d_in[6];
    const float* Wp = (const float*)d_in[7];
    const float* bp = (const float*)d_in[8];
    f16* wsf = (f16*)d_ws;
    wprep<<<1, 256, 0, stream>>>(Wq, Wk, Wv, Wp, wsf);
    wsa3d<<<1024, 256, 0, stream>>>(x, wsf, bq, bk, bv, bp, (float*)d_out);
}

// Round 16
// 70.941 us; speedup vs baseline: 1.6028x; 1.1638x over previous
//
#include <hip/hip_runtime.h>

typedef _Float16 f16;
typedef __attribute__((ext_vector_type(4))) _Float16 f16x4;
typedef __attribute__((ext_vector_type(8))) _Float16 f16x8;
typedef __attribute__((ext_vector_type(4))) float f32x4;

#define MFMA32(a,b,c) __builtin_amdgcn_mfma_f32_16x16x32_f16((a),(b),(c),0,0,0)
#define MFMA16(a,b,c) __builtin_amdgcn_mfma_f32_16x16x16f16((a),(b),(c),0,0,0)

// ---- pre-kernel: pack W{q,k,v,p} into per-lane f16 A-fragments in ws.
// frag c = m*8 + ob*2 + s (m: 0=q 1=k 2=v 3=p); lane l holds row ob*16+(l&15),
// k = 8*(l>>4) + 32*s + [0,8). Main-kernel loads: 16B/lane coalesced, L2-resident.
__global__ void wprep(const float* __restrict__ Wq, const float* __restrict__ Wk,
                      const float* __restrict__ Wv, const float* __restrict__ Wp,
                      f16* __restrict__ ws)
{
    const int t = threadIdx.x;
    const int lane = t & 63;
    const float* Wm[4] = {Wq, Wk, Wv, Wp};
    #pragma unroll
    for (int j = 0; j < 8; ++j) {
        const int c = (t >> 6) * 8 + j;
        const int m = c >> 3, ob = (c >> 1) & 3, s = c & 1;
        const float* src = Wm[m] + (ob * 16 + (lane & 15)) * 64 + 8 * (lane >> 4) + 32 * s;
        f32x4 a4 = *(const f32x4*)src;
        f32x4 b4 = *(const f32x4*)(src + 4);
        f16x8 h;
        #pragma unroll
        for (int ii = 0; ii < 8; ++ii) h[ii] = (f16)(ii < 4 ? a4[ii] : b4[ii - 4]);
        *(f16x8*)(ws + c * 512 + lane * 8) = h;
    }
}

// R16 = champion R8 + ONE surgical change: softmax denominator via ones-fragment
// MFMA (4x MFMA16 on the idle matrix pipe, overlapping PV) instead of 7 VALU adds
// + 2 serial shfl_xor per (h,ib). Everything else byte-identical to R8 (67.6us):
// LDS 32,768B xw->vv alias + SG out-staging alias, o_t LDS round-trip, MFMA32
// out-projection, 4-round staged coalesced scatter, bounds (256,3), grid 2048.
__global__ __launch_bounds__(256, 3)
void wsa3d(const float* __restrict__ x, const f16* __restrict__ wsf,
           const float* __restrict__ bq, const float* __restrict__ bk,
           const float* __restrict__ bv, const float* __restrict__ bp,
           float* __restrict__ out)
{
    __shared__ __align__(16) f16 lds[16384];
    f16*   const XW = lds;
    float* const SG = (float*)lds;

    const int tid  = threadIdx.x;
    const int lane = tid & 63;
    const int w    = tid >> 6;
    const int g    = lane >> 4;
    const int ln16 = lane & 15;
    const int key  = ln16 & 7;

    // XCD swizzle (2048 % 8 == 0 -> bijective): 256 consecutive quads per XCD
    const int bid = blockIdx.x;
    const int Q   = ((bid & 7) << 8) | (bid >> 3);
    const int qx = Q & 3, ih = (Q >> 2) & 15, idz = (Q >> 6) & 15, b = Q >> 10;

    const float c_sc = 0.25f * 1.44269504088896340736f;  // scale * log2(e)
    const f32x4 z4 = {0.f, 0.f, 0.f, 0.f};
    const f16x4 ones = {(f16)1.f, (f16)1.f, (f16)1.f, (f16)1.f};

    const int gz = (lane >> 4) & 3, gy = (lane >> 2) & 3, gq = lane & 3;

    // ---- gather (coalesced, 16 lines/inst); immediate f16 convert
    f16x4 valh[16];
    #pragma unroll
    for (int i = 0; i < 16; ++i) {
        const int c = w * 16 + i;
        f32x4 v4 = *(const f32x4*)(x + ((((b*64 + c)*64 + idz*4 + gz)*64) + ih*4 + gy)*64 + qx*16 + gq*4);
        #pragma unroll
        for (int r = 0; r < 4; ++r) valh[i][r] = (f16)v4[r];
    }

    // ---- transpose-pack -> xw of window gq (wave w supplies channels [16w,16w+16))
    #pragma unroll
    for (int lx = 0; lx < 4; ++lx) {
        const int t = gz * 16 + gy * 4 + lx;
        #pragma unroll
        for (int h2 = 0; h2 < 2; ++h2) {
            f16x8 pk;
            #pragma unroll
            for (int ii = 0; ii < 8; ++ii) pk[ii] = valh[h2 * 8 + ii][lx];
            *(f16x8*)(XW + gq*4096 + t*64 + (((w*2 + h2) ^ (t & 7) ^ gq) << 3)) = pk;
        }
    }
    __syncthreads();   // B1

    // ---- xw fragments (B for q/k proj, A for v^T proj)
    f16x8 xf[4][2];
    #pragma unroll
    for (int lb = 0; lb < 4; ++lb)
        #pragma unroll
        for (int s = 0; s < 2; ++s)
            xf[lb][s] = *(const f16x8*)(XW + w*4096 + (lb*16 + ln16)*64 + (((g + 4*s) ^ key ^ w) << 3));

    // ---- v^T projection -> vv[ch][tok] (same-wave overwrite of xw)
    #pragma unroll
    for (int ob = 0; ob < 4; ++ob) {
        f16x8 VF[2];
        #pragma unroll
        for (int s = 0; s < 2; ++s) VF[s] = *(const f16x8*)(wsf + (16 + ob*2 + s)*512 + lane*8);
        const float bvo = bv[ob * 16 + ln16];
        #pragma unroll
        for (int tb = 0; tb < 4; ++tb) {
            f32x4 a = z4;
            #pragma unroll
            for (int s = 0; s < 2; ++s) a = MFMA32(xf[tb][s], VF[s], a);
            f16x4 h4;
            #pragma unroll
            for (int r = 0; r < 4; ++r) h4[r] = (f16)(a[r] + bvo);
            *(f16x4*)(XW + w*4096 + (ob*16 + ln16)*64 + (((2*tb + (g >> 1)) ^ key ^ w) << 3) + 4*(g & 1)) = h4;
        }
    }

    // ---- attention, head-sequential, P fully in registers
    f16x4 ot[4][4];
    #pragma unroll
    for (int h = 0; h < 4; ++h) {
        f16x8 QF[2], KF[2];
        #pragma unroll
        for (int s = 0; s < 2; ++s) {
            QF[s] = *(const f16x8*)(wsf + (h*2 + s)*512 + lane*8);
            KF[s] = *(const f16x8*)(wsf + (8 + h*2 + s)*512 + lane*8);
        }
        const f32x4 bqv = *(const f32x4*)(bq + h*16 + g*4);
        const f32x4 bkv = *(const f32x4*)(bk + h*16 + g*4);
        // q/k proj: C-layout == K16 frag layout (lane: d=4g+r, tok=16lb+ln16)
        f16x4 qf[4], kf[4];
        #pragma unroll
        for (int lb = 0; lb < 4; ++lb) {
            f32x4 aq = z4, ak = z4;
            #pragma unroll
            for (int s = 0; s < 2; ++s) {
                aq = MFMA32(QF[s], xf[lb][s], aq);
                ak = MFMA32(KF[s], xf[lb][s], ak);
            }
            #pragma unroll
            for (int r = 0; r < 4; ++r) {
                qf[lb][r] = (f16)((aq[r] + bqv[r]) * c_sc);
                kf[lb][r] = (f16)(ak[r] + bkv[r]);
            }
        }
        // v A-fragments: row d = ch 16h+ln16, k = j = 16jb+4g+ii
        f16x4 va[4];
        #pragma unroll
        for (int jb = 0; jb < 4; ++jb)
            va[jb] = *(const f16x4*)(XW + w*4096 + (16*h + ln16)*64 + (((2*jb + (g >> 1)) ^ key ^ w) << 3) + 4*(g & 1));
        #pragma unroll
        for (int ib = 0; ib < 4; ++ib) {
            f16x4 pf[4];
            #pragma unroll
            for (int jb = 0; jb < 4; ++jb) {
                f32x4 S = MFMA16(kf[jb], qf[ib], z4);   // S^T: row=j(16jb+4g+r), col=i(16ib+ln16)
                #pragma unroll
                for (int r = 0; r < 4; ++r) pf[jb][r] = (f16)__builtin_amdgcn_exp2f(S[r]);
            }
            // denominator via ones-MFMA: every lane gets sum over all 64 j at col i=ln16
            // (matrix pipe, overlaps the PV chain; replaces 7 VALU adds + 2 serial shfls)
            f32x4 sm = z4;
            #pragma unroll
            for (int jb = 0; jb < 4; ++jb) sm = MFMA16(ones, pf[jb], sm);
            f32x4 O = z4;
            #pragma unroll
            for (int jb = 0; jb < 4; ++jb) O = MFMA16(va[jb], pf[jb], O);  // row=d(4g+r), col=i(ln16)
            const float inv = __builtin_amdgcn_rcpf(sm[0]);
            #pragma unroll
            for (int r = 0; r < 4; ++r) ot[h][ib][r] = (f16)(O[r] * inv);
        }
    }

    // ---- o_t[tok][ch] stores (vv dead; same-wave ordering)
    #pragma unroll
    for (int h = 0; h < 4; ++h)
        #pragma unroll
        for (int ib = 0; ib < 4; ++ib)
            *(f16x4*)(XW + w*4096 + (16*ib + ln16)*64 + (((2*h + (g >> 1)) ^ key ^ w) << 3) + 4*(g & 1)) = ot[h][ib];

    // ---- output projection: D2[t][o] = sum_c o_t[t][c] Wp[o][c]  (last XW reads)
    f16x8 PF[4][2];
    #pragma unroll
    for (int oc = 0; oc < 4; ++oc)
        #pragma unroll
        for (int s = 0; s < 2; ++s) PF[oc][s] = *(const f16x8*)(wsf + (24 + oc*2 + s)*512 + lane*8);
    float bps[4];
    #pragma unroll
    for (int oc = 0; oc < 4; ++oc) bps[oc] = bp[oc * 16 + ln16];

    f32x4 res[4][4];   // res[tb][oc]: t = 16tb+4g+r, o = 16oc+ln16
    #pragma unroll
    for (int tb = 0; tb < 4; ++tb) {
        f16x8 af[2];
        #pragma unroll
        for (int s = 0; s < 2; ++s)
            af[s] = *(const f16x8*)(XW + w*4096 + (tb*16 + ln16)*64 + (((g + 4*s) ^ key ^ w) << 3));
        #pragma unroll
        for (int oc = 0; oc < 4; ++oc) {
            f32x4 a = z4;
            #pragma unroll
            for (int s = 0; s < 2; ++s) a = MFMA32(af[s], PF[oc][s], a);
            #pragma unroll
            for (int r = 0; r < 4; ++r) res[tb][oc][r] = a[r] + bps[oc];
        }
    }
    __syncthreads();   // B_alias: all XW reads done (all waves) -> XW reusable as SG

    // ---- staged, coalesced scatter (4 oc rounds)
    #pragma unroll
    for (int oc = 0; oc < 4; ++oc) {
        #pragma unroll
        for (int tb = 0; tb < 4; ++tb)
            *(f32x4*)(SG + w*1092 + ln16*68 + ((tb*16 + g*4) ^ (w << 2))) = res[tb][oc];
        __syncthreads();
        #pragma unroll
        for (int si = 0; si < 4; ++si) {
            const int o2 = w * 4 + si;
            f32x4 v4 = *(const f32x4*)(SG + gq*1092 + o2*68 + ((gz*16 + gy*4) ^ (gq << 2)));
            *(f32x4*)(out + ((((b*64 + oc*16 + o2)*64 + idz*4 + gz)*64) + ih*4 + gy)*64 + qx*16 + gq*4) = v4;
        }
        if (oc < 3) __syncthreads();
    }
}

extern "C" void kernel_launch(void* const* d_in, const int* in_sizes, int n_in,
                              void* d_out, int out_size, void* d_ws, size_t ws_size,
                              hipStream_t stream) {
    (void)in_sizes; (void)n_in; (void)out_size; (void)ws_size;
    const float* x  = (const float*)d_in[0];
    const float* Wq = (const float*)d_in[1];
    const float* bq = (const float*)d_in[2];
    const float* Wk = (const float*)d_in[3];
    const float* bk = (const float*)d_in[4];
    const float* Wv = (const float*)d_in[5];
    const float* bv = (const float*)d_in[6];
    const float* Wp = (const float*)d_in[7];
    const float* bp = (const float*)d_in[8];
    f16* wsf = (f16*)d_ws;
    wprep<<<1, 256, 0, stream>>>(Wq, Wk, Wv, Wp, wsf);
    wsa3d<<<2048, 256, 0, stream>>>(x, wsf, bq, bk, bv, bp, (float*)d_out);
}